// Round 7
// baseline (73.932 us; speedup 1.0000x reference)
//
#include <hip/hip_runtime.h>

#define HDIM 256
#define SEQ 2048

typedef _Float16 half8_t __attribute__((ext_vector_type(8)));
typedef _Float16 half4_t __attribute__((ext_vector_type(4)));
typedef float floatx16 __attribute__((ext_vector_type(16)));

#define U_PITCH 512                       // bytes per U row (256 f16)
#define H_PITCH 512                       // bytes per h/x row (256 f16)
#define U_ROWS 79                         // 64 positions + 15 halo
#define HA0_OFF (U_ROWS * U_PITCH)        // 40448
#define LDS_BYTES (HA0_OFF + 4 * 16384)   // 105984 -> 1 WG/CU

static __device__ __forceinline__ float exp2f_fast(float x) {
  float r; asm("v_exp_f32 %0, %1" : "=v"(r) : "v"(x)); return r;
}
static __device__ __forceinline__ float rcpf_fast(float x) {
  float r; asm("v_rcp_f32 %0, %1" : "=v"(r) : "v"(x)); return r;
}
// tanh(x) = 1 - 2/(exp2(2*log2e*x)+1); saturates correctly at +-inf.
static __device__ __forceinline__ float tanhf_fast(float x) {
  float e = exp2f_fast(x * 2.8853900817779268f);
  return 1.0f - 2.0f * rcpf_fast(e + 1.0f);
}
static __device__ __forceinline__ unsigned pkh(float a, float b) {
  return __builtin_bit_cast(unsigned, __builtin_amdgcn_cvt_pkrtz(a, b));
}

// 8 waves/WG (512 thr). WG owns 64 positions = tile0 (pos 0-31) + tile1
// (pos 32-63). Wave w: tile t = w&1, j-slice [64*(w>>1), +64) (Wf[2][16]).
// The two j-half MFMA chains per wave are independent (in-wave ILP, R6's
// proven lever) and SHARE the h ds_read -> h-read LDS traffic halves vs R6.
// MFMA: D[j][p] = sum_k W[j][k] * h[p][k]  (A-op = W rows, B-op = h^T).
// A-frag: lane holds A[l&31][(l>>5)*8+i]; B-frag: B[(l>>5)*8+i][l&31];
// C/D:    col = l&31 (=p), row j_local = (r&3) + 8*(r>>2) + 4*(l>>5).
// NOTE: __launch_bounds__ 2nd arg = min BLOCKS/CU on this toolchain (R3).
__global__ __launch_bounds__(512, 1) void winrnn_kernel(
    const float* __restrict__ x, const float* __restrict__ W_ih,
    const float* __restrict__ W_hh, const float* __restrict__ b_ih,
    const float* __restrict__ b_hh, float* __restrict__ out) {
  extern __shared__ char smem[];
  const int tid = threadIdx.x;
  const int w = tid >> 6;
  const int lane = tid & 63;
  const int l31 = lane & 31;
  const int hi = lane >> 5;

  const int wg = blockIdx.x;
  const int batch = wg >> 5;                 // 32 tile-groups (64 pos) per batch
  const int t0 = (wg & 31) * 64;
  const float* xb = x + (size_t)batch * SEQ * HDIM;

  const int t = w & 1;                       // tile (position half)
  const int jbase = (w >> 1) * 64;           // 64-wide j-slice
  const int tb = t * 32;                     // tile base row within WG
  const int hswz = l31 << 4;

  // h buffers: tile tt, buffer bb at HA0_OFF + tt*32768 + bb*16384
  char* const hbuf = smem + HA0_OFF + t * 32768;

  // ---- stage x rows [t0-15, t0+64) as f16 (rows 79..95 zeroed), swizzled,
  //      into the h-buffer region ----
  {
    char* xl = smem + HA0_OFF;
#pragma unroll
    for (int it = 0; it < 12; ++it) {
      int idx = tid + it * 512;              // 96 rows * 64 float4-chunks
      int row = idx >> 6;
      int c4 = idx & 63;
      int xi = t0 - 15 + row;
      float4 v = make_float4(0.f, 0.f, 0.f, 0.f);
      if (row < U_ROWS && xi >= 0)
        v = *reinterpret_cast<const float4*>(xb + (size_t)xi * HDIM + c4 * 4);
      uint2 u;
      u.x = pkh(v.x, v.y);
      u.y = pkh(v.z, v.w);
      *reinterpret_cast<uint2*>(xl + row * H_PITCH + ((c4 * 8) ^ ((row & 31) << 4))) = u;
    }
  }

  // ---- W_ih fragments (f32 -> f16), 64 j-rows per wave ----
  half8_t Wf[2][16];
#pragma unroll
  for (int jt = 0; jt < 2; ++jt)
#pragma unroll
    for (int kt = 0; kt < 16; ++kt) {
      const float* wp = W_ih + (size_t)(jbase + jt * 32 + l31) * HDIM + kt * 16 + hi * 8;
      float4 a = *reinterpret_cast<const float4*>(wp);
      float4 b = *reinterpret_cast<const float4*>(wp + 4);
      uint4 uu;
      uu.x = pkh(a.x, a.y); uu.y = pkh(a.z, a.w);
      uu.z = pkh(b.x, b.y); uu.w = pkh(b.z, b.w);
      Wf[jt][kt] = __builtin_bit_cast(half8_t, uu);
    }

  // ---- bias (b_ih + b_hh) in D-fragment layout ----
  float4 biasf[2][4];
#pragma unroll
  for (int jt = 0; jt < 2; ++jt)
#pragma unroll
    for (int g = 0; g < 4; ++g) {
      int j0 = jbase + jt * 32 + g * 8 + hi * 4;
      float4 bi = *reinterpret_cast<const float4*>(b_ih + j0);
      float4 bh = *reinterpret_cast<const float4*>(b_hh + j0);
      biasf[jt][g] = make_float4(bi.x + bh.x, bi.y + bh.y, bi.z + bh.z, bi.w + bh.w);
    }

  __syncthreads();

  // ---- U = x @ W_ih^T + bias (f16, swizzled LDS) ----
  // Row-tiles s in {0,1,2} split by tile bit: t=0 -> {0,2}, t=1 -> {1}.
  {
    const char* xl = smem + HA0_OFF;
    char* Ul = smem;
    for (int s = t; s < 3; s += 2) {
      int prow = s * 32 + l31;
      floatx16 acc0, acc1;
#pragma unroll
      for (int g = 0; g < 4; ++g) {
        acc0[4*g+0] = biasf[0][g].x; acc0[4*g+1] = biasf[0][g].y;
        acc0[4*g+2] = biasf[0][g].z; acc0[4*g+3] = biasf[0][g].w;
        acc1[4*g+0] = biasf[1][g].x; acc1[4*g+1] = biasf[1][g].y;
        acc1[4*g+2] = biasf[1][g].z; acc1[4*g+3] = biasf[1][g].w;
      }
#pragma unroll
      for (int kt = 0; kt < 16; ++kt) {
        half8_t xB = *reinterpret_cast<const half8_t*>(
            xl + prow * H_PITCH + ((kt * 32 + hi * 16) ^ ((prow & 31) << 4)));
        acc0 = __builtin_amdgcn_mfma_f32_32x32x16_f16(Wf[0][kt], xB, acc0, 0, 0, 0);
        acc1 = __builtin_amdgcn_mfma_f32_32x32x16_f16(Wf[1][kt], xB, acc1, 0, 0, 0);
      }
      if (prow < U_ROWS) {
        int uswz = (prow & 31) << 4;
#pragma unroll
        for (int jt = 0; jt < 2; ++jt)
#pragma unroll
          for (int g = 0; g < 4; ++g) {
            const floatx16& ac = jt ? acc1 : acc0;
            uint2 st;
            st.x = pkh(ac[4*g+0], ac[4*g+1]);
            st.y = pkh(ac[4*g+2], ac[4*g+3]);
            int j0 = jbase + jt * 32 + g * 8 + hi * 4;
            *reinterpret_cast<uint2*>(Ul + prow * U_PITCH + ((j0 * 2) ^ uswz)) = st;
          }
      }
    }
  }

  // ---- reload Wf with W_hh (register-only) ----
#pragma unroll
  for (int jt = 0; jt < 2; ++jt)
#pragma unroll
    for (int kt = 0; kt < 16; ++kt) {
      const float* wp = W_hh + (size_t)(jbase + jt * 32 + l31) * HDIM + kt * 16 + hi * 8;
      float4 a = *reinterpret_cast<const float4*>(wp);
      float4 b = *reinterpret_cast<const float4*>(wp + 4);
      uint4 uu;
      uu.x = pkh(a.x, a.y); uu.y = pkh(a.z, a.w);
      uu.z = pkh(b.x, b.y); uu.w = pkh(b.z, b.w);
      Wf[jt][kt] = __builtin_bit_cast(half8_t, uu);
    }

  __syncthreads();

  // ---- 16-step recurrence; two j-half chains share each h ds_read ----
  const char* Ul = smem;
  floatx16 acc0, acc1;
  for (int k = 0; k < 16; ++k) {
    const int urow = tb + l31 + k;           // 0..78
    const int uswz = (urow & 31) << 4;
#pragma unroll
    for (int g = 0; g < 4; ++g) {
      int j00 = (jbase + g * 8 + hi * 4) * 2;
      half4_t u0 = __builtin_bit_cast(half4_t, *reinterpret_cast<const uint2*>(
          Ul + urow * U_PITCH + (j00 ^ uswz)));
      half4_t u1 = __builtin_bit_cast(half4_t, *reinterpret_cast<const uint2*>(
          Ul + urow * U_PITCH + ((j00 + 64) ^ uswz)));
      acc0[4*g+0] = (float)u0[0]; acc0[4*g+1] = (float)u0[1];
      acc0[4*g+2] = (float)u0[2]; acc0[4*g+3] = (float)u0[3];
      acc1[4*g+0] = (float)u1[0]; acc1[4*g+1] = (float)u1[1];
      acc1[4*g+2] = (float)u1[2]; acc1[4*g+3] = (float)u1[3];
    }
    if (k > 0) {
      const char* hr = hbuf + ((k & 1) ? 0 : 16384);  // buffer written by k-1
#pragma unroll
      for (int kt = 0; kt < 16; ++kt) {
        half8_t hB = *reinterpret_cast<const half8_t*>(
            hr + l31 * H_PITCH + ((kt * 32 + hi * 16) ^ hswz));
        acc0 = __builtin_amdgcn_mfma_f32_32x32x16_f16(Wf[0][kt], hB, acc0, 0, 0, 0);
        acc1 = __builtin_amdgcn_mfma_f32_32x32x16_f16(Wf[1][kt], hB, acc1, 0, 0, 0);
      }
    }
    if (k < 15) {
      char* hw = hbuf + ((k & 1) ? 16384 : 0);
#pragma unroll
      for (int jt = 0; jt < 2; ++jt) {
        const floatx16& ac = jt ? acc1 : acc0;
#pragma unroll
        for (int g = 0; g < 4; ++g) {
          float ta = tanhf_fast(ac[4*g+0]);
          float tb2 = tanhf_fast(ac[4*g+1]);
          float tc = tanhf_fast(ac[4*g+2]);
          float td = tanhf_fast(ac[4*g+3]);
          uint2 u; u.x = pkh(ta, tb2); u.y = pkh(tc, td);
          int jb = (jbase + jt * 32 + g * 8 + hi * 4) * 2;
          *reinterpret_cast<uint2*>(hw + l31 * H_PITCH + (jb ^ hswz)) = u;
        }
      }
      __syncthreads();
    }
  }

  // ---- epilogue: final tanh -> f32 staged in LDS -> coalesced out ----
  __syncthreads();   // all step-15 h reads complete before overwrite
  {
    char* ol = smem + HA0_OFF;               // 64 rows x 1024 B = 65536
    const int orow = tb + l31;
    const int oswz = (orow & 31) << 4;
#pragma unroll
    for (int jt = 0; jt < 2; ++jt) {
      const floatx16& ac = jt ? acc1 : acc0;
#pragma unroll
      for (int g = 0; g < 4; ++g) {
        float4 st;
        st.x = tanhf_fast(ac[4*g+0]); st.y = tanhf_fast(ac[4*g+1]);
        st.z = tanhf_fast(ac[4*g+2]); st.w = tanhf_fast(ac[4*g+3]);
        int jb4 = (jbase + jt * 32 + g * 8 + hi * 4) * 4;
        *reinterpret_cast<float4*>(ol + orow * 1024 + (jb4 ^ oswz)) = st;
      }
    }
  }
  __syncthreads();
  {
    const char* ol = smem + HA0_OFF;
    float* ob = out + ((size_t)batch * SEQ + t0) * HDIM;
#pragma unroll
    for (int it = 0; it < 8; ++it) {
      int idx = tid + it * 512;               // 64 rows * 64 chunks
      int row = idx >> 6;
      int c = idx & 63;
      float4 v = *reinterpret_cast<const float4*>(
          ol + row * 1024 + ((c * 16) ^ ((row & 31) << 4)));
      *reinterpret_cast<float4*>(ob + (size_t)row * HDIM + c * 4) = v;
    }
  }
}

extern "C" void kernel_launch(void* const* d_in, const int* in_sizes, int n_in,
                              void* d_out, int out_size, void* d_ws, size_t ws_size,
                              hipStream_t stream) {
  const float* x    = (const float*)d_in[0];
  const float* W_ih = (const float*)d_in[1];
  const float* W_hh = (const float*)d_in[2];
  const float* b_ih = (const float*)d_in[3];
  const float* b_hh = (const float*)d_in[4];
  float* out = (float*)d_out;
  static_assert(LDS_BYTES <= 160 * 1024, "LDS budget");
  hipFuncSetAttribute(reinterpret_cast<const void*>(winrnn_kernel),
                      hipFuncAttributeMaxDynamicSharedMemorySize, LDS_BYTES);
  winrnn_kernel<<<dim3(256), dim3(512), LDS_BYTES, stream>>>(x, W_ih, W_hh, b_ih, b_hh, out);
}

// Round 8
// 61.320 us; speedup vs baseline: 1.2057x; 1.2057x over previous
//
#include <hip/hip_runtime.h>

#define HDIM 256
#define SEQ 2048

typedef _Float16 half8_t __attribute__((ext_vector_type(8)));
typedef float floatx16 __attribute__((ext_vector_type(16)));

#define U_PITCH 1024                     // bytes per U row (256 f32)
#define H_PITCH 512                      // bytes per h/x row (256 f16)
#define U_ROWS 79                        // 64 positions + 15 halo
#define HA0_OFF (U_ROWS * U_PITCH)       // 80896
#define HA1_OFF (HA0_OFF + 16384)
#define HB0_OFF (HA0_OFF + 32768)
#define HB1_OFF (HA0_OFF + 49152)
#define LDS_BYTES (HA0_OFF + 65536)      // 146432 <= 163840 -> 1 WG/CU

static __device__ __forceinline__ float exp2f_fast(float x) {
  float r; asm("v_exp_f32 %0, %1" : "=v"(r) : "v"(x)); return r;
}
static __device__ __forceinline__ float rcpf_fast(float x) {
  float r; asm("v_rcp_f32 %0, %1" : "=v"(r) : "v"(x)); return r;
}
// tanh(x) = 1 - 2/(exp2(2*log2e*x)+1); 3 VALU + 2 trans, saturates at +-inf.
static __device__ __forceinline__ float tanhf_fast(float x) {
  float e = exp2f_fast(x * 2.8853900817779268f);
  return 1.0f - 2.0f * rcpf_fast(e + 1.0f);
}
static __device__ __forceinline__ unsigned pkh(float a, float b) {
  return __builtin_bit_cast(unsigned, __builtin_amdgcn_cvt_pkrtz(a, b));
}

// 8 waves/WG (512 thr); wave w owns j in [32w, 32w+32) for BOTH tiles.
// WG owns 64 positions = tile A (t0..t0+31) + tile B (t0+32..t0+63).
// R6 lever: independent in-wave load->MFMA streams. R8 doubles them: each
// tile's chain is depth-split (kt 0-7 -> acc, kt 8-15 -> acc2, summed before
// tanh) -> 4 independent streams/wave, chain depth 8. U[k+1] is prefetched
// into registers BEFORE the step-k barrier (U region is read-only during the
// recurrence), removing the post-barrier ds_read latency from the chain.
// MFMA: D[j][p] = sum_k W[j][k] * h[p][k]  (A-op = W rows, B-op = h^T).
// A-frag: lane holds A[l&31][(l>>5)*8+i]; B-frag: B[(l>>5)*8+i][l&31];
// C/D:    col = l&31 (=p), row j_local = (r&3) + 8*(r>>2) + 4*(l>>5).
// NOTE: __launch_bounds__ 2nd arg = min BLOCKS/CU on this toolchain (R3:
// (512,4) capped VGPR at 64 -> spill). (512,1): no cap pressure.
__global__ __launch_bounds__(512, 1) void winrnn_kernel(
    const float* __restrict__ x, const float* __restrict__ W_ih,
    const float* __restrict__ W_hh, const float* __restrict__ b_ih,
    const float* __restrict__ b_hh, float* __restrict__ out) {
  extern __shared__ char smem[];
  const int tid = threadIdx.x;
  const int w = tid >> 6;
  const int lane = tid & 63;
  const int l31 = lane & 31;
  const int hi = lane >> 5;

  const int wg = blockIdx.x;
  const int batch = wg >> 5;                 // 32 tile-groups (64 pos) per batch
  const int t0 = (wg & 31) * 64;
  const float* xb = x + (size_t)batch * SEQ * HDIM;

  const int jbase = w * 32;
  const int hswz = l31 << 4;

  // ---- stage x rows [t0-15, t0+64) as f16 (rows 79..95 zeroed), swizzled,
  //      into the h-buffer region ----
  {
    char* xl = smem + HA0_OFF;
#pragma unroll
    for (int it = 0; it < 12; ++it) {
      int idx = tid + it * 512;              // 96 rows * 64 float4-chunks
      int row = idx >> 6;
      int c4 = idx & 63;
      int xi = t0 - 15 + row;
      float4 v = make_float4(0.f, 0.f, 0.f, 0.f);
      if (row < U_ROWS && xi >= 0)
        v = *reinterpret_cast<const float4*>(xb + (size_t)xi * HDIM + c4 * 4);
      uint2 u;
      u.x = pkh(v.x, v.y);
      u.y = pkh(v.z, v.w);
      *reinterpret_cast<uint2*>(xl + row * H_PITCH + ((c4 * 8) ^ ((row & 31) << 4))) = u;
    }
  }

  // ---- W_ih fragments (f32 -> f16), 32 j-rows per wave ----
  half8_t Wf[16];
#pragma unroll
  for (int kt = 0; kt < 16; ++kt) {
    const float* wp = W_ih + (size_t)(jbase + l31) * HDIM + kt * 16 + hi * 8;
    float4 a = *reinterpret_cast<const float4*>(wp);
    float4 b = *reinterpret_cast<const float4*>(wp + 4);
    uint4 uu;
    uu.x = pkh(a.x, a.y); uu.y = pkh(a.z, a.w);
    uu.z = pkh(b.x, b.y); uu.w = pkh(b.z, b.w);
    Wf[kt] = __builtin_bit_cast(half8_t, uu);
  }

  // ---- bias (b_ih + b_hh) in D-fragment layout ----
  float4 biasf[4];
#pragma unroll
  for (int g = 0; g < 4; ++g) {
    int j0 = jbase + g * 8 + hi * 4;
    float4 bi = *reinterpret_cast<const float4*>(b_ih + j0);
    float4 bh = *reinterpret_cast<const float4*>(b_hh + j0);
    biasf[g] = make_float4(bi.x + bh.x, bi.y + bh.y, bi.z + bh.z, bi.w + bh.w);
  }

  __syncthreads();

  // ---- U = x @ W_ih^T + bias (f32, swizzled); 3 row-tiles of 32 ----
  {
    const char* xl = smem + HA0_OFF;
    char* Ul = smem;
#pragma unroll
    for (int s = 0; s < 3; ++s) {
      int prow = s * 32 + l31;
      floatx16 acc;
#pragma unroll
      for (int g = 0; g < 4; ++g) {
        acc[4*g+0] = biasf[g].x; acc[4*g+1] = biasf[g].y;
        acc[4*g+2] = biasf[g].z; acc[4*g+3] = biasf[g].w;
      }
#pragma unroll
      for (int kt = 0; kt < 16; ++kt) {
        half8_t xB = *reinterpret_cast<const half8_t*>(
            xl + prow * H_PITCH + ((kt * 32 + hi * 16) ^ ((prow & 31) << 4)));
        acc = __builtin_amdgcn_mfma_f32_32x32x16_f16(Wf[kt], xB, acc, 0, 0, 0);
      }
      if (prow < U_ROWS) {
        int uswz = (prow & 31) << 4;
#pragma unroll
        for (int g = 0; g < 4; ++g) {
          int j0 = jbase + g * 8 + hi * 4;
          float4 st;
          st.x = acc[4*g+0]; st.y = acc[4*g+1]; st.z = acc[4*g+2]; st.w = acc[4*g+3];
          *reinterpret_cast<float4*>(Ul + prow * U_PITCH + ((j0 * 4) ^ uswz)) = st;
        }
      }
    }
  }

  // ---- reload Wf with W_hh (register-only) ----
#pragma unroll
  for (int kt = 0; kt < 16; ++kt) {
    const float* wp = W_hh + (size_t)(jbase + l31) * HDIM + kt * 16 + hi * 8;
    float4 a = *reinterpret_cast<const float4*>(wp);
    float4 b = *reinterpret_cast<const float4*>(wp + 4);
    uint4 uu;
    uu.x = pkh(a.x, a.y); uu.y = pkh(a.z, a.w);
    uu.z = pkh(b.x, b.y); uu.w = pkh(b.z, b.w);
    Wf[kt] = __builtin_bit_cast(half8_t, uu);
  }

  __syncthreads();

  // ---- 16-step recurrence; tiles A,B x depth-split = 4 streams/wave ----
  const char* Ul = smem;
  floatx16 accA, accB, accA2, accB2;
  float4 uA[4], uB[4];
  // preload U[k=0]
  {
    const int urowA = l31;
    const int urowB = 32 + l31;
    const int uswzA = (urowA & 31) << 4;
    const int uswzB = (urowB & 31) << 4;
#pragma unroll
    for (int g = 0; g < 4; ++g) {
      int j00 = (jbase + g * 8 + hi * 4) * 4;
      uA[g] = *reinterpret_cast<const float4*>(Ul + urowA * U_PITCH + (j00 ^ uswzA));
      uB[g] = *reinterpret_cast<const float4*>(Ul + urowB * U_PITCH + (j00 ^ uswzB));
    }
  }

  for (int k = 0; k < 16; ++k) {
    // init from prefetched U; split accumulators start at 0
#pragma unroll
    for (int g = 0; g < 4; ++g) {
      accA[4*g+0] = uA[g].x; accA[4*g+1] = uA[g].y;
      accA[4*g+2] = uA[g].z; accA[4*g+3] = uA[g].w;
      accB[4*g+0] = uB[g].x; accB[4*g+1] = uB[g].y;
      accB[4*g+2] = uB[g].z; accB[4*g+3] = uB[g].w;
      accA2[4*g+0] = 0.f; accA2[4*g+1] = 0.f; accA2[4*g+2] = 0.f; accA2[4*g+3] = 0.f;
      accB2[4*g+0] = 0.f; accB2[4*g+1] = 0.f; accB2[4*g+2] = 0.f; accB2[4*g+3] = 0.f;
    }
    if (k > 0) {
      const char* hrA = smem + ((k & 1) ? HA0_OFF : HA1_OFF);
      const char* hrB = smem + ((k & 1) ? HB0_OFF : HB1_OFF);
#pragma unroll
      for (int kt = 0; kt < 8; ++kt) {
        int off0 = (kt * 32 + hi * 16) ^ hswz;
        int off1 = ((kt + 8) * 32 + hi * 16) ^ hswz;
        half8_t a0 = *reinterpret_cast<const half8_t*>(hrA + l31 * H_PITCH + off0);
        half8_t a1 = *reinterpret_cast<const half8_t*>(hrA + l31 * H_PITCH + off1);
        half8_t b0 = *reinterpret_cast<const half8_t*>(hrB + l31 * H_PITCH + off0);
        half8_t b1 = *reinterpret_cast<const half8_t*>(hrB + l31 * H_PITCH + off1);
        accA  = __builtin_amdgcn_mfma_f32_32x32x16_f16(Wf[kt],     a0, accA,  0, 0, 0);
        accA2 = __builtin_amdgcn_mfma_f32_32x32x16_f16(Wf[kt + 8], a1, accA2, 0, 0, 0);
        accB  = __builtin_amdgcn_mfma_f32_32x32x16_f16(Wf[kt],     b0, accB,  0, 0, 0);
        accB2 = __builtin_amdgcn_mfma_f32_32x32x16_f16(Wf[kt + 8], b1, accB2, 0, 0, 0);
      }
    }
    if (k < 15) {
      // prefetch U[k+1] into registers (read-only region; crosses the barrier)
      {
        const int urowA = l31 + k + 1;
        const int urowB = 32 + l31 + k + 1;
        const int uswzA = (urowA & 31) << 4;
        const int uswzB = (urowB & 31) << 4;
#pragma unroll
        for (int g = 0; g < 4; ++g) {
          int j00 = (jbase + g * 8 + hi * 4) * 4;
          uA[g] = *reinterpret_cast<const float4*>(Ul + urowA * U_PITCH + (j00 ^ uswzA));
          uB[g] = *reinterpret_cast<const float4*>(Ul + urowB * U_PITCH + (j00 ^ uswzB));
        }
      }
      char* hwA = smem + ((k & 1) ? HA1_OFF : HA0_OFF);
      char* hwB = smem + ((k & 1) ? HB1_OFF : HB0_OFF);
#pragma unroll
      for (int g = 0; g < 4; ++g) {
        float a0 = tanhf_fast(accA[4*g+0] + accA2[4*g+0]);
        float a1 = tanhf_fast(accA[4*g+1] + accA2[4*g+1]);
        float a2 = tanhf_fast(accA[4*g+2] + accA2[4*g+2]);
        float a3 = tanhf_fast(accA[4*g+3] + accA2[4*g+3]);
        float b0 = tanhf_fast(accB[4*g+0] + accB2[4*g+0]);
        float b1 = tanhf_fast(accB[4*g+1] + accB2[4*g+1]);
        float b2 = tanhf_fast(accB[4*g+2] + accB2[4*g+2]);
        float b3 = tanhf_fast(accB[4*g+3] + accB2[4*g+3]);
        int jb = (jbase + g * 8 + hi * 4) * 2;
        uint2 ua; ua.x = pkh(a0, a1); ua.y = pkh(a2, a3);
        uint2 ub; ub.x = pkh(b0, b1); ub.y = pkh(b2, b3);
        *reinterpret_cast<uint2*>(hwA + l31 * H_PITCH + (jb ^ hswz)) = ua;
        *reinterpret_cast<uint2*>(hwB + l31 * H_PITCH + (jb ^ hswz)) = ub;
      }
      __syncthreads();
    }
  }
  accA += accA2;
  accB += accB2;

  // ---- epilogue: final tanh -> f32 staged in LDS (h region) -> coalesced out ----
  __syncthreads();   // all step-15 h reads complete before overwrite
  {
    char* ol = smem + HA0_OFF;               // 64 rows x 1024 B = 65536
    const int oswzA = (l31 & 31) << 4;
    const int oswzB = ((32 + l31) & 31) << 4;
#pragma unroll
    for (int g = 0; g < 4; ++g) {
      float4 sa, sb;
      sa.x = tanhf_fast(accA[4*g+0]); sa.y = tanhf_fast(accA[4*g+1]);
      sa.z = tanhf_fast(accA[4*g+2]); sa.w = tanhf_fast(accA[4*g+3]);
      sb.x = tanhf_fast(accB[4*g+0]); sb.y = tanhf_fast(accB[4*g+1]);
      sb.z = tanhf_fast(accB[4*g+2]); sb.w = tanhf_fast(accB[4*g+3]);
      int jb4 = (jbase + g * 8 + hi * 4) * 4;
      *reinterpret_cast<float4*>(ol + l31 * 1024 + (jb4 ^ oswzA)) = sa;
      *reinterpret_cast<float4*>(ol + (32 + l31) * 1024 + (jb4 ^ oswzB)) = sb;
    }
  }
  __syncthreads();
  {
    const char* ol = smem + HA0_OFF;
    float* ob = out + ((size_t)batch * SEQ + t0) * HDIM;
#pragma unroll
    for (int it = 0; it < 8; ++it) {
      int idx = tid + it * 512;               // 64 rows * 64 chunks
      int row = idx >> 6;
      int c = idx & 63;
      float4 v = *reinterpret_cast<const float4*>(
          ol + row * 1024 + ((c * 16) ^ ((row & 31) << 4)));
      *reinterpret_cast<float4*>(ob + (size_t)row * HDIM + c * 4) = v;
    }
  }
}

extern "C" void kernel_launch(void* const* d_in, const int* in_sizes, int n_in,
                              void* d_out, int out_size, void* d_ws, size_t ws_size,
                              hipStream_t stream) {
  const float* x    = (const float*)d_in[0];
  const float* W_ih = (const float*)d_in[1];
  const float* W_hh = (const float*)d_in[2];
  const float* b_ih = (const float*)d_in[3];
  const float* b_hh = (const float*)d_in[4];
  float* out = (float*)d_out;
  static_assert(LDS_BYTES <= 160 * 1024, "LDS budget");
  hipFuncSetAttribute(reinterpret_cast<const void*>(winrnn_kernel),
                      hipFuncAttributeMaxDynamicSharedMemorySize, LDS_BYTES);
  winrnn_kernel<<<dim3(256), dim3(512), LDS_BYTES, stream>>>(x, W_ih, W_hh, b_ih, b_hh, out);
}